// Round 17
// baseline (274.841 us; speedup 1.0000x reference)
//
#include <hip/hip_runtime.h>
#include <cstdint>
#include <cstddef>

typedef unsigned short u16;
typedef __bf16 bf16x8 __attribute__((ext_vector_type(8)));
typedef float f32x4 __attribute__((ext_vector_type(4)));
typedef unsigned short u16x4 __attribute__((ext_vector_type(4)));
typedef unsigned short u16x8 __attribute__((ext_vector_type(8)));
typedef uint32_t u32x4 __attribute__((ext_vector_type(4)));
typedef __attribute__((address_space(1))) unsigned int as1_uint;
typedef __attribute__((address_space(3))) unsigned int as3_uint;

__device__ __forceinline__ u16 f2bf(float f) {
  uint32_t u = __builtin_bit_cast(uint32_t, f);
  u += 0x7FFFu + ((u >> 16) & 1u);   // RNE to bf16
  return (u16)(u >> 16);
}

// one-instruction packed f32x2 -> bf16x2 (RNE), T12 recipe
__device__ __forceinline__ uint32_t cvtpk2bf(float a, float b) {
  uint32_t r;
  asm("v_cvt_pk_bf16_f32 %0, %1, %2" : "=v"(r) : "v"(a), "v"(b));
  return r;
}

__device__ __forceinline__ float max3f(float a, float b, float c) {
  return fmaxf(fmaxf(a, b), c);   // clang fuses to v_max3_f32
}

__device__ __forceinline__ void gld_lds16(const void* g, void* l) {
  __builtin_amdgcn_global_load_lds((as1_uint*)g, (as3_uint*)l, 16, 0, 0);
}

// ---------------- fused prep: weight transposes (z<4) + x cast (z>=4) ----------------
__global__ __launch_bounds__(256) void k_prep(const float* __restrict__ x,
                                              u16* __restrict__ xb,
                                              const float* __restrict__ Wq,
                                              const float* __restrict__ Wk,
                                              const float* __restrict__ Wv,
                                              const float* __restrict__ Wo,
                                              u16* __restrict__ wqkvT,
                                              u16* __restrict__ woT) {
  constexpr int K = 2048;
  const int z = blockIdx.z;
  if (z >= 4) {
    int i = ((z - 4) * 1024 + blockIdx.y * 32 + blockIdx.x) * 256 + threadIdx.x;
    const float4* p = reinterpret_cast<const float4*>(x) + (size_t)i * 2;
    float4 a = p[0], b = p[1];
    u16x8 r;
    r[0] = f2bf(a.x); r[1] = f2bf(a.y); r[2] = f2bf(a.z); r[3] = f2bf(a.w);
    r[4] = f2bf(b.x); r[5] = f2bf(b.y); r[6] = f2bf(b.z); r[7] = f2bf(b.w);
    *reinterpret_cast<u16x8*>(xb + (size_t)i * 8) = r;
    return;
  }
  const float* W; u16* Wt; int N;
  if (z == 0)      { W = Wq; Wt = wqkvT;                        N = 2048; }
  else if (z == 1) { W = Wo; Wt = woT;                          N = 2048; }
  else if (z == 2) { W = Wk; Wt = wqkvT + (size_t)2048 * 2048;  N = 512;  }
  else             { W = Wv; Wt = wqkvT + (size_t)2560 * 2048;  N = 512;  }
  const int n0 = blockIdx.x * 64;
  if (n0 >= N) return;
  __shared__ u16 tile[64][72];
  const int k0 = blockIdx.y * 64;
  const int r = threadIdx.x >> 4;
  const int c4 = (threadIdx.x & 15) * 4;
#pragma unroll
  for (int i = 0; i < 4; ++i) {
    int kk = r + i * 16;
    float4 v = *reinterpret_cast<const float4*>(W + (size_t)(k0 + kk) * N + n0 + c4);
    tile[kk][c4 + 0] = f2bf(v.x); tile[kk][c4 + 1] = f2bf(v.y);
    tile[kk][c4 + 2] = f2bf(v.z); tile[kk][c4 + 3] = f2bf(v.w);
  }
  __syncthreads();
#pragma unroll
  for (int i = 0; i < 4; ++i) {
    int nn = r + i * 16;
    u16x4 o;
    o[0] = tile[c4 + 0][nn]; o[1] = tile[c4 + 1][nn];
    o[2] = tile[c4 + 2][nn]; o[3] = tile[c4 + 3][nn];
    *reinterpret_cast<u16x4*>(Wt + (size_t)(n0 + nn) * K + k0 + c4) = o;
  }
}

// ---------------- bf16 GEMM: C = (A @ Bt^T + bias(col)) * colscale ----------------
// 128x128 tile, BK=64, 4 waves (2x2), 16x16x32 MFMA; T1 bijective XCD swizzle.
// Columns >= vcol0 (bf16 out only) are written TRANSPOSED to vout[b][kvh][d][token].
template <bool F32OUT>
__global__ __launch_bounds__(256) void k_gemm(const u16* __restrict__ A,
                                              const u16* __restrict__ Bt,
                                              const float* __restrict__ b0,
                                              const float* __restrict__ b1,
                                              const float* __restrict__ b2,
                                              void* __restrict__ Cout,
                                              int M, int N, int K,
                                              int n1, int n2,
                                              int scaleN, float scaleV,
                                              u16* __restrict__ vout, int vcol0, int ldC) {
  __shared__ __align__(16) u16 As[128 * 64];
  __shared__ __align__(16) u16 Bs[128 * 64];
  const int id = blockIdx.y * gridDim.x + blockIdx.x;
  const int cpx = (gridDim.x * gridDim.y) >> 3;
  const int nid = (id & 7) * cpx + (id >> 3);
  const int m0 = (nid / gridDim.x) * 128, n0 = (nid % gridDim.x) * 128;
  const int tid = threadIdx.x;
  const int l = tid & 63, w = tid >> 6;
  const int wm = w >> 1, wn = w & 1;
  const int lr = l & 15, lo = l >> 4;
  const int srow = w * 8 + (l >> 3);
  const int sc = (l & 7) ^ ((l >> 3) & 7);
  f32x4 acc[4][4] = {};
  for (int kt = 0; kt < K; kt += 64) {
    __syncthreads();
#pragma unroll
    for (int it = 0; it < 4; ++it) {
      int row = it * 32 + srow;
      gld_lds16(A + (size_t)(m0 + row) * K + kt + sc * 8,
                (char*)As + (it * 32 + w * 8) * 128);
      gld_lds16(Bt + (size_t)(n0 + row) * K + kt + sc * 8,
                (char*)Bs + (it * 32 + w * 8) * 128);
    }
    __syncthreads();
    bf16x8 af[4][2], bfr[4][2];
#pragma unroll
    for (int mi = 0; mi < 4; ++mi) {
      int row = wm * 64 + mi * 16 + lr;
#pragma unroll
      for (int ks = 0; ks < 2; ++ks) {
        int ch = (ks * 4 + lo) ^ (row & 7);
        af[mi][ks] = *reinterpret_cast<const bf16x8*>((const char*)As + row * 128 + ch * 16);
      }
    }
#pragma unroll
    for (int nj = 0; nj < 4; ++nj) {
      int row = wn * 64 + nj * 16 + lr;
#pragma unroll
      for (int ks = 0; ks < 2; ++ks) {
        int ch = (ks * 4 + lo) ^ (row & 7);
        bfr[nj][ks] = *reinterpret_cast<const bf16x8*>((const char*)Bs + row * 128 + ch * 16);
      }
    }
#pragma unroll
    for (int mi = 0; mi < 4; ++mi)
#pragma unroll
      for (int nj = 0; nj < 4; ++nj) {
        acc[mi][nj] = __builtin_amdgcn_mfma_f32_16x16x32_bf16(af[mi][0], bfr[nj][0], acc[mi][nj], 0, 0, 0);
        acc[mi][nj] = __builtin_amdgcn_mfma_f32_16x16x32_bf16(af[mi][1], bfr[nj][1], acc[mi][nj], 0, 0, 0);
      }
  }
#pragma unroll
  for (int mi = 0; mi < 4; ++mi) {
    int row = m0 + wm * 64 + mi * 16 + lo * 4;
#pragma unroll
    for (int nj = 0; nj < 4; ++nj) {
      int col = n0 + wn * 64 + nj * 16 + lr;
      float bv = (col < n1) ? b0[col] : (col < n2 ? b1[col - n1] : b2[col - n2]);
      float scc = (col < scaleN) ? scaleV : 1.0f;
      float v[4];
#pragma unroll
      for (int r = 0; r < 4; ++r) v[r] = (acc[mi][nj][r] + bv) * scc;
      if (!F32OUT && col >= vcol0) {
        int d = col - vcol0;
        int kvh = d >> 6, dcol = d & 63;
        int bb = row >> 11, token = row & 2047;
        u16x4 o;
#pragma unroll
        for (int r = 0; r < 4; ++r) o[r] = f2bf(v[r]);
        *reinterpret_cast<u16x4*>(vout + (((size_t)(bb * 8 + kvh) * 64 + dcol) * 2048 + token)) = o;
      } else {
#pragma unroll
        for (int r = 0; r < 4; ++r) {
          if (F32OUT) ((float*)Cout)[(size_t)(row + r) * ldC + col] = v[r];
          else        ((u16*)Cout)[(size_t)(row + r) * ldC + col] = f2bf(v[r]);
        }
      }
    }
  }
}

// ---------------- flash attention: 512 threads, 8 waves x 16 q-rows, KVBLK=128 ----------------
// grid (S/128, NQ, B); HD=64. launch_bounds(512,2) -> VGPR cap 128.
// 128-key tile = TWO verified 64-key sub-tiles (identical swizzle/fragment math to R15);
// one barrier + one prefetch batch + one defer-ballot per 128 keys. The two sub-tiles'
// softmax chains are independent -> ILP hides shfl/exp2 latency. Defer-max THR=8 (verified).
__global__ __launch_bounds__(512, 2) void k_attn(const u16* __restrict__ QKV,
                                                 const u16* __restrict__ VT,
                                                 u16* __restrict__ Oa) {
  constexpr int S = 2048, LDQ = 2560;
  constexpr float THR = 8.0f;
  __shared__ __align__(16) u16 Ks[2][2][64 * 64];   // [buf][khalf][key][d], chunk ^= row&7
  __shared__ __align__(16) u16 Vs[2][2][64 * 64];   // [buf][khalf][d][key], chunk ^= row&7
  const int qt = blockIdx.x, h = blockIdx.y, b = blockIdx.z;
  const int kvh = h >> 2;
  const int tid = threadIdx.x, l = tid & 63, w = tid >> 6;   // w = 0..7
  const int lr = l & 15, lo = l >> 4;
  const size_t base = (size_t)b * S * LDQ;
  const u16* Qg = QKV + base + h * 64;
  const u16* Kg = QKV + base + 2048 + kvh * 64;
  const u16* Vg = VT + (size_t)(b * 8 + kvh) * 64 * 2048;
  const int qrow = qt * 128 + w * 16 + lr;
  const bf16x8 aq0 = *reinterpret_cast<const bf16x8*>(Qg + (size_t)qrow * LDQ + lo * 8);
  const bf16x8 aq1 = *reinterpret_cast<const bf16x8*>(Qg + (size_t)qrow * LDQ + 32 + lo * 8);
  // all-ones bf16 B-frag (layout-proof: every element 1.0)
  u32x4 onesw; onesw[0] = 0x3F803F80u; onesw[1] = 0x3F803F80u; onesw[2] = 0x3F803F80u; onesw[3] = 0x3F803F80u;
  const bf16x8 ones = __builtin_bit_cast(bf16x8, onesw);
  f32x4 acc[4] = {};
  f32x4 lsum4 = {};                              // row-sum in acc layout: lsum4[r] for q=lo*4+r
  float mrun = -1e30f;
  const int krow = tid >> 3;                     // rows 0..63 across 8 waves
  const int ksc = (l & 7) ^ ((l >> 3) & 7);
  // ---- prologue: stage tile 0 (4 issues cover 128 keys of K and V) ----
  gld_lds16(Kg + (size_t)krow * LDQ + ksc * 8,           (char*)Ks[0][0] + (w * 8) * 128);
  gld_lds16(Kg + (size_t)(64 + krow) * LDQ + ksc * 8,    (char*)Ks[0][1] + (w * 8) * 128);
  gld_lds16(Vg + (size_t)krow * 2048 + ksc * 8,          (char*)Vs[0][0] + (w * 8) * 128);
  gld_lds16(Vg + (size_t)krow * 2048 + 64 + ksc * 8,     (char*)Vs[0][1] + (w * 8) * 128);
  int cur = 0;
  for (int kt = 0; kt < S; kt += 128) {
    __syncthreads();   // implicit vmcnt(0): buf[cur] (both halves) ready
    if (kt + 128 < S) { // prefetch next 128-key tile; in flight across compute
      const int nb = cur ^ 1, nk = kt + 128;
      gld_lds16(Kg + (size_t)(nk + krow) * LDQ + ksc * 8,        (char*)Ks[nb][0] + (w * 8) * 128);
      gld_lds16(Kg + (size_t)(nk + 64 + krow) * LDQ + ksc * 8,   (char*)Ks[nb][1] + (w * 8) * 128);
      gld_lds16(Vg + (size_t)krow * 2048 + nk + ksc * 8,         (char*)Vs[nb][0] + (w * 8) * 128);
      gld_lds16(Vg + (size_t)krow * 2048 + nk + 64 + ksc * 8,    (char*)Vs[nb][1] + (w * 8) * 128);
    }
    // QK^T swapped, both halves: p0/p1[t*4+r] = S[key=half*64+16t+4lo+r][q=lr]
    float p0[16], p1[16];
    const u16* K0 = Ks[cur][0];
    const u16* K1 = Ks[cur][1];
    __builtin_amdgcn_s_setprio(1);
#pragma unroll
    for (int t = 0; t < 4; ++t) {
      const int row = t * 16 + lr;
      const int c0 = (lo ^ (row & 7)) * 16, c1 = ((4 + lo) ^ (row & 7)) * 16;
      bf16x8 k00 = *reinterpret_cast<const bf16x8*>((const char*)K0 + row * 128 + c0);
      bf16x8 k01 = *reinterpret_cast<const bf16x8*>((const char*)K0 + row * 128 + c1);
      bf16x8 k10 = *reinterpret_cast<const bf16x8*>((const char*)K1 + row * 128 + c0);
      bf16x8 k11 = *reinterpret_cast<const bf16x8*>((const char*)K1 + row * 128 + c1);
      f32x4 z0 = {}, z1 = {};
      z0 = __builtin_amdgcn_mfma_f32_16x16x32_bf16(k00, aq0, z0, 0, 0, 0);
      z0 = __builtin_amdgcn_mfma_f32_16x16x32_bf16(k01, aq1, z0, 0, 0, 0);
      z1 = __builtin_amdgcn_mfma_f32_16x16x32_bf16(k10, aq0, z1, 0, 0, 0);
      z1 = __builtin_amdgcn_mfma_f32_16x16x32_bf16(k11, aq1, z1, 0, 0, 0);
#pragma unroll
      for (int r = 0; r < 4; ++r) { p0[t * 4 + r] = z0[r]; p1[t * 4 + r] = z1[r]; }
    }
    __builtin_amdgcn_s_setprio(0);
    // per-q tile max over both halves (two independent chains -> ILP)
    float a0 = max3f(p0[0], p0[1], p0[2]);
    float a1 = max3f(p0[3], p0[4], p0[5]);
    float a2 = max3f(p0[6], p0[7], p0[8]);
    float a3 = max3f(p0[9], p0[10], p0[11]);
    float a4 = max3f(p0[12], p0[13], p0[14]);
    float tm0 = fmaxf(max3f(a0, a1, a2), max3f(a3, a4, p0[15]));
    float b0m = max3f(p1[0], p1[1], p1[2]);
    float b1m = max3f(p1[3], p1[4], p1[5]);
    float b2m = max3f(p1[6], p1[7], p1[8]);
    float b3m = max3f(p1[9], p1[10], p1[11]);
    float b4m = max3f(p1[12], p1[13], p1[14]);
    float tm1 = fmaxf(max3f(b0m, b1m, b2m), max3f(b3m, b4m, p1[15]));
    tm0 = fmaxf(tm0, __shfl_xor(tm0, 16, 64));
    tm1 = fmaxf(tm1, __shfl_xor(tm1, 16, 64));
    tm0 = fmaxf(tm0, __shfl_xor(tm0, 32, 64));
    tm1 = fmaxf(tm1, __shfl_xor(tm1, 32, 64));
    float tm = fmaxf(tm0, tm1);
    if (__all(tm <= mrun + THR)) {
      // defer-max: keep stale mrun; p bounded by 2^THR
#pragma unroll
      for (int i = 0; i < 16; ++i) { p0[i] = __builtin_amdgcn_exp2f(p0[i] - mrun);
                                     p1[i] = __builtin_amdgcn_exp2f(p1[i] - mrun); }
    } else {
      float mnew = fmaxf(mrun, tm);
      float alpha = __builtin_amdgcn_exp2f(mrun - mnew);
      mrun = mnew;
#pragma unroll
      for (int i = 0; i < 16; ++i) { p0[i] = __builtin_amdgcn_exp2f(p0[i] - mnew);
                                     p1[i] = __builtin_amdgcn_exp2f(p1[i] - mnew); }
#pragma unroll
      for (int r = 0; r < 4; ++r) {
        float ar = __shfl(alpha, lo * 4 + r, 64);   // alpha for acc-row q=lo*4+r
        lsum4[r] *= ar;
#pragma unroll
        for (int nj = 0; nj < 4; ++nj) acc[nj][r] *= ar;
      }
    }
    // pack P pairs (1 instr each) and redistribute to A-frag layout via permlane swaps
    uint32_t w00 = cvtpk2bf(p0[0], p0[1]),   w01 = cvtpk2bf(p0[2], p0[3]);
    uint32_t w10 = cvtpk2bf(p0[4], p0[5]),   w11 = cvtpk2bf(p0[6], p0[7]);
    uint32_t w20 = cvtpk2bf(p0[8], p0[9]),   w21 = cvtpk2bf(p0[10], p0[11]);
    uint32_t w30 = cvtpk2bf(p0[12], p0[13]), w31 = cvtpk2bf(p0[14], p0[15]);
    uint32_t x00 = cvtpk2bf(p1[0], p1[1]),   x01 = cvtpk2bf(p1[2], p1[3]);
    uint32_t x10 = cvtpk2bf(p1[4], p1[5]),   x11 = cvtpk2bf(p1[6], p1[7]);
    uint32_t x20 = cvtpk2bf(p1[8], p1[9]),   x21 = cvtpk2bf(p1[10], p1[11]);
    uint32_t x30 = cvtpk2bf(p1[12], p1[13]), x31 = cvtpk2bf(p1[14], p1[15]);
    asm volatile("v_permlane32_swap_b32 %0, %1" : "+v"(w00), "+v"(w10));
    asm volatile("v_permlane16_swap_b32 %0, %1" : "+v"(w00), "+v"(w10));
    asm volatile("v_permlane32_swap_b32 %0, %1" : "+v"(w01), "+v"(w11));
    asm volatile("v_permlane16_swap_b32 %0, %1" : "+v"(w01), "+v"(w11));
    asm volatile("v_permlane32_swap_b32 %0, %1" : "+v"(w20), "+v"(w30));
    asm volatile("v_permlane16_swap_b32 %0, %1" : "+v"(w20), "+v"(w30));
    asm volatile("v_permlane32_swap_b32 %0, %1" : "+v"(w21), "+v"(w31));
    asm volatile("v_permlane16_swap_b32 %0, %1" : "+v"(w21), "+v"(w31));
    asm volatile("v_permlane32_swap_b32 %0, %1" : "+v"(x00), "+v"(x10));
    asm volatile("v_permlane16_swap_b32 %0, %1" : "+v"(x00), "+v"(x10));
    asm volatile("v_permlane32_swap_b32 %0, %1" : "+v"(x01), "+v"(x11));
    asm volatile("v_permlane16_swap_b32 %0, %1" : "+v"(x01), "+v"(x11));
    asm volatile("v_permlane32_swap_b32 %0, %1" : "+v"(x20), "+v"(x30));
    asm volatile("v_permlane16_swap_b32 %0, %1" : "+v"(x20), "+v"(x30));
    asm volatile("v_permlane32_swap_b32 %0, %1" : "+v"(x21), "+v"(x31));
    asm volatile("v_permlane16_swap_b32 %0, %1" : "+v"(x21), "+v"(x31));
    u32x4 pq0; pq0[0] = w00; pq0[1] = w01; pq0[2] = w10; pq0[3] = w11;
    u32x4 pq1; pq1[0] = w20; pq1[1] = w21; pq1[2] = w30; pq1[3] = w31;
    u32x4 pq2; pq2[0] = x00; pq2[1] = x01; pq2[2] = x10; pq2[3] = x11;
    u32x4 pq3; pq3[0] = x20; pq3[1] = x21; pq3[2] = x30; pq3[3] = x31;
    const bf16x8 pa0 = __builtin_bit_cast(bf16x8, pq0);
    const bf16x8 pa1 = __builtin_bit_cast(bf16x8, pq1);
    const bf16x8 pa2 = __builtin_bit_cast(bf16x8, pq2);
    const bf16x8 pa3 = __builtin_bit_cast(bf16x8, pq3);
    const u16* V0 = Vs[cur][0];
    const u16* V1 = Vs[cur][1];
    __builtin_amdgcn_s_setprio(1);
    // row-sum via MFMA: lsum4[r] += sum_k P[q=lo*4+r][k]
    lsum4 = __builtin_amdgcn_mfma_f32_16x16x32_bf16(pa0, ones, lsum4, 0, 0, 0);
    lsum4 = __builtin_amdgcn_mfma_f32_16x16x32_bf16(pa1, ones, lsum4, 0, 0, 0);
    lsum4 = __builtin_amdgcn_mfma_f32_16x16x32_bf16(pa2, ones, lsum4, 0, 0, 0);
    lsum4 = __builtin_amdgcn_mfma_f32_16x16x32_bf16(pa3, ones, lsum4, 0, 0, 0);
#pragma unroll
    for (int nj = 0; nj < 4; ++nj) {
      const int vr = nj * 16 + lr;   // d row
      const int c0 = (lo ^ (vr & 7)) * 16, c1 = ((4 + lo) ^ (vr & 7)) * 16;
      const bf16x8 bv00 = *reinterpret_cast<const bf16x8*>((const char*)V0 + vr * 128 + c0);
      const bf16x8 bv01 = *reinterpret_cast<const bf16x8*>((const char*)V0 + vr * 128 + c1);
      const bf16x8 bv10 = *reinterpret_cast<const bf16x8*>((const char*)V1 + vr * 128 + c0);
      const bf16x8 bv11 = *reinterpret_cast<const bf16x8*>((const char*)V1 + vr * 128 + c1);
      acc[nj] = __builtin_amdgcn_mfma_f32_16x16x32_bf16(pa0, bv00, acc[nj], 0, 0, 0);
      acc[nj] = __builtin_amdgcn_mfma_f32_16x16x32_bf16(pa1, bv01, acc[nj], 0, 0, 0);
      acc[nj] = __builtin_amdgcn_mfma_f32_16x16x32_bf16(pa2, bv10, acc[nj], 0, 0, 0);
      acc[nj] = __builtin_amdgcn_mfma_f32_16x16x32_bf16(pa3, bv11, acc[nj], 0, 0, 0);
    }
    __builtin_amdgcn_s_setprio(0);
    cur ^= 1;
  }
  float lf[4];
#pragma unroll
  for (int r = 0; r < 4; ++r) lf[r] = 1.0f / lsum4[r];
  const size_t orow = (size_t)b * S + qt * 128 + w * 16 + lo * 4;
#pragma unroll
  for (int nj = 0; nj < 4; ++nj) {
    const int col = h * 64 + nj * 16 + lr;
#pragma unroll
    for (int r = 0; r < 4; ++r)
      Oa[(orow + r) * 2048 + col] = f2bf(acc[nj][r] * lf[r]);
  }
}

// ---------------- host ----------------
extern "C" void kernel_launch(void* const* d_in, const int* in_sizes, int n_in,
                              void* d_out, int out_size, void* d_ws, size_t ws_size,
                              hipStream_t stream) {
  const float* x  = (const float*)d_in[0];
  const float* Wq = (const float*)d_in[1];
  const float* bq = (const float*)d_in[2];
  const float* Wk = (const float*)d_in[3];
  const float* bk = (const float*)d_in[4];
  const float* Wv = (const float*)d_in[5];
  const float* bv = (const float*)d_in[6];
  const float* Wo = (const float*)d_in[7];
  const float* bo = (const float*)d_in[8];
  float* out = (float*)d_out;
  char* ws = (char*)d_ws;

  u16*   xb    = (u16*)(ws + 0);           // [4096][2048] bf16   16.78 MB
  u16*   wqkvT = (u16*)(ws + 16777216);    // [3072][2048] bf16   12.58 MB
  u16*   woT   = (u16*)(ws + 29360128);    // [2048][2048] bf16    8.39 MB
  u16*   qkv   = (u16*)(ws + 37748736);    // [4096][2560] bf16   20.97 MB (Q|K only)
  u16*   attn  = (u16*)(ws + 58720256);    // [4096][2048] bf16   16.78 MB
  u16*   vtg   = (u16*)(ws + 75497472);    // [2][8][64][2048] bf16 4.19 MB (V transposed)

  const float SCL = 0.125f * 1.44269504088896341f;  // 1/sqrt(64) * log2(e)

  k_prep<<<dim3(32, 32, 8), 256, 0, stream>>>(x, xb, Wq, Wk, Wv, Wo, wqkvT, woT);
  k_gemm<false><<<dim3(24, 32), 256, 0, stream>>>(xb, wqkvT, bq, bk, bv, qkv,
                                                  4096, 3072, 2048, 2048, 2560, 2048, SCL,
                                                  vtg, 2560, 2560);
  k_attn<<<dim3(16, 32, 2), 512, 0, stream>>>(qkv, vtg, attn);
  k_gemm<true><<<dim3(16, 32), 256, 0, stream>>>(attn, woT, bo, bo, bo, out,
                                                 4096, 2048, 2048, 2048, 4096, 0, 1.0f,
                                                 nullptr, 1 << 30, 2048);
}

// Round 18
// 248.244 us; speedup vs baseline: 1.1071x; 1.1071x over previous
//
#include <hip/hip_runtime.h>
#include <cstdint>
#include <cstddef>

typedef unsigned short u16;
typedef __bf16 bf16x8 __attribute__((ext_vector_type(8)));
typedef float f32x4 __attribute__((ext_vector_type(4)));
typedef unsigned short u16x4 __attribute__((ext_vector_type(4)));
typedef unsigned short u16x8 __attribute__((ext_vector_type(8)));
typedef uint32_t u32x4 __attribute__((ext_vector_type(4)));
typedef __attribute__((address_space(1))) unsigned int as1_uint;
typedef __attribute__((address_space(3))) unsigned int as3_uint;

__device__ __forceinline__ u16 f2bf(float f) {
  uint32_t u = __builtin_bit_cast(uint32_t, f);
  u += 0x7FFFu + ((u >> 16) & 1u);   // RNE to bf16
  return (u16)(u >> 16);
}

// one-instruction packed f32x2 -> bf16x2 (RNE), T12 recipe
__device__ __forceinline__ uint32_t cvtpk2bf(float a, float b) {
  uint32_t r;
  asm("v_cvt_pk_bf16_f32 %0, %1, %2" : "=v"(r) : "v"(a), "v"(b));
  return r;
}

__device__ __forceinline__ float max3f(float a, float b, float c) {
  return fmaxf(fmaxf(a, b), c);   // clang fuses to v_max3_f32
}

__device__ __forceinline__ void gld_lds16(const void* g, void* l) {
  __builtin_amdgcn_global_load_lds((as1_uint*)g, (as3_uint*)l, 16, 0, 0);
}

// ---------------- fused prep: weight transposes (z<4) + x cast (z>=4) ----------------
__global__ __launch_bounds__(256) void k_prep(const float* __restrict__ x,
                                              u16* __restrict__ xb,
                                              const float* __restrict__ Wq,
                                              const float* __restrict__ Wk,
                                              const float* __restrict__ Wv,
                                              const float* __restrict__ Wo,
                                              u16* __restrict__ wqkvT,
                                              u16* __restrict__ woT) {
  constexpr int K = 2048;
  const int z = blockIdx.z;
  if (z >= 4) {
    int i = ((z - 4) * 1024 + blockIdx.y * 32 + blockIdx.x) * 256 + threadIdx.x;
    const float4* p = reinterpret_cast<const float4*>(x) + (size_t)i * 2;
    float4 a = p[0], b = p[1];
    u16x8 r;
    r[0] = f2bf(a.x); r[1] = f2bf(a.y); r[2] = f2bf(a.z); r[3] = f2bf(a.w);
    r[4] = f2bf(b.x); r[5] = f2bf(b.y); r[6] = f2bf(b.z); r[7] = f2bf(b.w);
    *reinterpret_cast<u16x8*>(xb + (size_t)i * 8) = r;
    return;
  }
  const float* W; u16* Wt; int N;
  if (z == 0)      { W = Wq; Wt = wqkvT;                        N = 2048; }
  else if (z == 1) { W = Wo; Wt = woT;                          N = 2048; }
  else if (z == 2) { W = Wk; Wt = wqkvT + (size_t)2048 * 2048;  N = 512;  }
  else             { W = Wv; Wt = wqkvT + (size_t)2560 * 2048;  N = 512;  }
  const int n0 = blockIdx.x * 64;
  if (n0 >= N) return;
  __shared__ u16 tile[64][72];
  const int k0 = blockIdx.y * 64;
  const int r = threadIdx.x >> 4;
  const int c4 = (threadIdx.x & 15) * 4;
#pragma unroll
  for (int i = 0; i < 4; ++i) {
    int kk = r + i * 16;
    float4 v = *reinterpret_cast<const float4*>(W + (size_t)(k0 + kk) * N + n0 + c4);
    tile[kk][c4 + 0] = f2bf(v.x); tile[kk][c4 + 1] = f2bf(v.y);
    tile[kk][c4 + 2] = f2bf(v.z); tile[kk][c4 + 3] = f2bf(v.w);
  }
  __syncthreads();
#pragma unroll
  for (int i = 0; i < 4; ++i) {
    int nn = r + i * 16;
    u16x4 o;
    o[0] = tile[c4 + 0][nn]; o[1] = tile[c4 + 1][nn];
    o[2] = tile[c4 + 2][nn]; o[3] = tile[c4 + 3][nn];
    *reinterpret_cast<u16x4*>(Wt + (size_t)(n0 + nn) * K + k0 + c4) = o;
  }
}

// ---------------- bf16 GEMM: C = (A @ Bt^T + bias(col)) * colscale ----------------
// 128x128 tile, BK=64, 4 waves (2x2), 16x16x32 MFMA; T1 bijective XCD swizzle.
// Columns >= vcol0 (bf16 out only) are written TRANSPOSED to vout[b][kvh][d][token].
template <bool F32OUT>
__global__ __launch_bounds__(256) void k_gemm(const u16* __restrict__ A,
                                              const u16* __restrict__ Bt,
                                              const float* __restrict__ b0,
                                              const float* __restrict__ b1,
                                              const float* __restrict__ b2,
                                              void* __restrict__ Cout,
                                              int M, int N, int K,
                                              int n1, int n2,
                                              int scaleN, float scaleV,
                                              u16* __restrict__ vout, int vcol0, int ldC) {
  __shared__ __align__(16) u16 As[128 * 64];
  __shared__ __align__(16) u16 Bs[128 * 64];
  const int id = blockIdx.y * gridDim.x + blockIdx.x;
  const int cpx = (gridDim.x * gridDim.y) >> 3;
  const int nid = (id & 7) * cpx + (id >> 3);
  const int m0 = (nid / gridDim.x) * 128, n0 = (nid % gridDim.x) * 128;
  const int tid = threadIdx.x;
  const int l = tid & 63, w = tid >> 6;
  const int wm = w >> 1, wn = w & 1;
  const int lr = l & 15, lo = l >> 4;
  const int srow = w * 8 + (l >> 3);
  const int sc = (l & 7) ^ ((l >> 3) & 7);
  f32x4 acc[4][4] = {};
  for (int kt = 0; kt < K; kt += 64) {
    __syncthreads();
#pragma unroll
    for (int it = 0; it < 4; ++it) {
      int row = it * 32 + srow;
      gld_lds16(A + (size_t)(m0 + row) * K + kt + sc * 8,
                (char*)As + (it * 32 + w * 8) * 128);
      gld_lds16(Bt + (size_t)(n0 + row) * K + kt + sc * 8,
                (char*)Bs + (it * 32 + w * 8) * 128);
    }
    __syncthreads();
    bf16x8 af[4][2], bfr[4][2];
#pragma unroll
    for (int mi = 0; mi < 4; ++mi) {
      int row = wm * 64 + mi * 16 + lr;
#pragma unroll
      for (int ks = 0; ks < 2; ++ks) {
        int ch = (ks * 4 + lo) ^ (row & 7);
        af[mi][ks] = *reinterpret_cast<const bf16x8*>((const char*)As + row * 128 + ch * 16);
      }
    }
#pragma unroll
    for (int nj = 0; nj < 4; ++nj) {
      int row = wn * 64 + nj * 16 + lr;
#pragma unroll
      for (int ks = 0; ks < 2; ++ks) {
        int ch = (ks * 4 + lo) ^ (row & 7);
        bfr[nj][ks] = *reinterpret_cast<const bf16x8*>((const char*)Bs + row * 128 + ch * 16);
      }
    }
#pragma unroll
    for (int mi = 0; mi < 4; ++mi)
#pragma unroll
      for (int nj = 0; nj < 4; ++nj) {
        acc[mi][nj] = __builtin_amdgcn_mfma_f32_16x16x32_bf16(af[mi][0], bfr[nj][0], acc[mi][nj], 0, 0, 0);
        acc[mi][nj] = __builtin_amdgcn_mfma_f32_16x16x32_bf16(af[mi][1], bfr[nj][1], acc[mi][nj], 0, 0, 0);
      }
  }
#pragma unroll
  for (int mi = 0; mi < 4; ++mi) {
    int row = m0 + wm * 64 + mi * 16 + lo * 4;
#pragma unroll
    for (int nj = 0; nj < 4; ++nj) {
      int col = n0 + wn * 64 + nj * 16 + lr;
      float bv = (col < n1) ? b0[col] : (col < n2 ? b1[col - n1] : b2[col - n2]);
      float scc = (col < scaleN) ? scaleV : 1.0f;
      float v[4];
#pragma unroll
      for (int r = 0; r < 4; ++r) v[r] = (acc[mi][nj][r] + bv) * scc;
      if (!F32OUT && col >= vcol0) {
        int d = col - vcol0;
        int kvh = d >> 6, dcol = d & 63;
        int bb = row >> 11, token = row & 2047;
        u16x4 o;
#pragma unroll
        for (int r = 0; r < 4; ++r) o[r] = f2bf(v[r]);
        *reinterpret_cast<u16x4*>(vout + (((size_t)(bb * 8 + kvh) * 64 + dcol) * 2048 + token)) = o;
      } else {
#pragma unroll
        for (int r = 0; r < 4; ++r) {
          if (F32OUT) ((float*)Cout)[(size_t)(row + r) * ldC + col] = v[r];
          else        ((u16*)Cout)[(size_t)(row + r) * ldC + col] = f2bf(v[r]);
        }
      }
    }
  }
}

// ---------------- flash attention: 512 threads, 8 waves x 16 q-rows ----------------
// grid (S/128, NQ, B); KVBLK=64; HD=64. launch_bounds(512,4). (R15 structure; R17's
// KVBLK=128 cut occupancy to 1 block/CU and regressed — 2 blocks/CU is required.)
// Fast-path ballot on PARTIAL maxima: __all(partial<=thr) <=> full-max<=thr for every q,
// so the 2 shfl_xor max-reductions move into the RARE rescale branch (critical path cut).
__global__ __launch_bounds__(512, 4) void k_attn(const u16* __restrict__ QKV,
                                                 const u16* __restrict__ VT,
                                                 u16* __restrict__ Oa) {
  constexpr int S = 2048, LDQ = 2560;
  constexpr float THR = 8.0f;
  __shared__ __align__(16) u16 Ks[2][64 * 64];   // [key][d], chunk ^= row&7
  __shared__ __align__(16) u16 Vs[2][64 * 64];   // [d][key], chunk ^= row&7
  const int qt = blockIdx.x, h = blockIdx.y, b = blockIdx.z;
  const int kvh = h >> 2;
  const int tid = threadIdx.x, l = tid & 63, w = tid >> 6;   // w = 0..7
  const int lr = l & 15, lo = l >> 4;
  const size_t base = (size_t)b * S * LDQ;
  const u16* Qg = QKV + base + h * 64;
  const u16* Kg = QKV + base + 2048 + kvh * 64;
  const u16* Vg = VT + (size_t)(b * 8 + kvh) * 64 * 2048;
  const int qrow = qt * 128 + w * 16 + lr;
  const bf16x8 aq0 = *reinterpret_cast<const bf16x8*>(Qg + (size_t)qrow * LDQ + lo * 8);
  const bf16x8 aq1 = *reinterpret_cast<const bf16x8*>(Qg + (size_t)qrow * LDQ + 32 + lo * 8);
  // all-ones bf16 B-frag (layout-proof: every element 1.0)
  u32x4 onesw; onesw[0] = 0x3F803F80u; onesw[1] = 0x3F803F80u; onesw[2] = 0x3F803F80u; onesw[3] = 0x3F803F80u;
  const bf16x8 ones = __builtin_bit_cast(bf16x8, onesw);
  f32x4 acc[4] = {};
  f32x4 lsum4 = {};                              // row-sum in acc layout: lsum4[r] for q=lo*4+r
  float mrun = -1e30f;                           // per-q running max (uniform across lo group)
  const int krow = tid >> 3;                     // rows 0..63 across 8 waves
  const int ksc = (l & 7) ^ ((l >> 3) & 7);
  // ---- prologue: stage tile 0 (1 issue per operand covers all 64 rows) ----
  gld_lds16(Kg + (size_t)krow * LDQ + ksc * 8, (char*)Ks[0] + (w * 8) * 128);
  gld_lds16(Vg + (size_t)krow * 2048 + ksc * 8, (char*)Vs[0] + (w * 8) * 128);
  int cur = 0;
  for (int kt = 0; kt < S; kt += 64) {
    __syncthreads();   // implicit vmcnt(0): buf[cur] (K+V) ready
    if (kt + 64 < S) { // prefetch tile t+1; in flight across compute(t)
      const int nb = cur ^ 1, nk = kt + 64;
      gld_lds16(Kg + (size_t)(nk + krow) * LDQ + ksc * 8, (char*)Ks[nb] + (w * 8) * 128);
      gld_lds16(Vg + (size_t)krow * 2048 + nk + ksc * 8, (char*)Vs[nb] + (w * 8) * 128);
    }
    // QK^T swapped: p[t*4+r] = S[key=16t+4lo+r][q=lr]  (Q pre-scaled by log2e/sqrt(HD))
    float p[16];
    const u16* KsC = Ks[cur];
    __builtin_amdgcn_s_setprio(1);
#pragma unroll
    for (int t = 0; t < 4; ++t) {
      const int row = t * 16 + lr;
      bf16x8 k0 = *reinterpret_cast<const bf16x8*>((const char*)KsC + row * 128 + ((lo ^ (row & 7)) * 16));
      bf16x8 k1 = *reinterpret_cast<const bf16x8*>((const char*)KsC + row * 128 + (((4 + lo) ^ (row & 7)) * 16));
      f32x4 zz = {};
      zz = __builtin_amdgcn_mfma_f32_16x16x32_bf16(k0, aq0, zz, 0, 0, 0);
      zz = __builtin_amdgcn_mfma_f32_16x16x32_bf16(k1, aq1, zz, 0, 0, 0);
#pragma unroll
      for (int r = 0; r < 4; ++r) p[t * 4 + r] = zz[r];
    }
    __builtin_amdgcn_s_setprio(0);
    // partial (in-lane) tile max for q=lr: max3 tree only — NO cross-lane ops
    float m0 = max3f(p[0], p[1], p[2]);
    float m1 = max3f(p[3], p[4], p[5]);
    float m2 = max3f(p[6], p[7], p[8]);
    float m3 = max3f(p[9], p[10], p[11]);
    float m4 = max3f(p[12], p[13], p[14]);
    float tmp = fmaxf(max3f(m0, m1, m2), max3f(m3, m4, p[15]));
    // __all over partial maxima == "full per-q max <= thr for every q" (proof: full max
    // is max over the 4 lanes' partials; __all quantifies over all lanes)
    if (__all(tmp <= mrun + THR)) {
      // defer-max: keep stale mrun; p bounded by 2^THR
#pragma unroll
      for (int i = 0; i < 16; ++i) p[i] = __builtin_amdgcn_exp2f(p[i] - mrun);
    } else {
      // rare path: full cross-lane reduce, then rescale
      float tm = fmaxf(tmp, __shfl_xor(tmp, 16, 64));
      tm = fmaxf(tm, __shfl_xor(tm, 32, 64));
      float mnew = fmaxf(mrun, tm);
      float alpha = __builtin_amdgcn_exp2f(mrun - mnew);
      mrun = mnew;
#pragma unroll
      for (int i = 0; i < 16; ++i) p[i] = __builtin_amdgcn_exp2f(p[i] - mnew);
#pragma unroll
      for (int r = 0; r < 4; ++r) {
        float ar = __shfl(alpha, lo * 4 + r, 64);   // alpha for acc-row q=lo*4+r
        lsum4[r] *= ar;
#pragma unroll
        for (int nj = 0; nj < 4; ++nj) acc[nj][r] *= ar;
      }
    }
    // pack P pairs with v_cvt_pk_bf16_f32 (1 instr each)
    uint32_t w00 = cvtpk2bf(p[0], p[1]),   w01 = cvtpk2bf(p[2], p[3]);
    uint32_t w10 = cvtpk2bf(p[4], p[5]),   w11 = cvtpk2bf(p[6], p[7]);
    uint32_t w20 = cvtpk2bf(p[8], p[9]),   w21 = cvtpk2bf(p[10], p[11]);
    uint32_t w30 = cvtpk2bf(p[12], p[13]), w31 = cvtpk2bf(p[14], p[15]);
    // redistribute to A-frag layout: lane lo needs keys 8lo..8lo+7 (pa0), +32 (pa1)
    asm volatile("v_permlane32_swap_b32 %0, %1" : "+v"(w00), "+v"(w10));
    asm volatile("v_permlane16_swap_b32 %0, %1" : "+v"(w00), "+v"(w10));  // w00=d0 w10=d2
    asm volatile("v_permlane32_swap_b32 %0, %1" : "+v"(w01), "+v"(w11));
    asm volatile("v_permlane16_swap_b32 %0, %1" : "+v"(w01), "+v"(w11));  // w01=d1 w11=d3
    asm volatile("v_permlane32_swap_b32 %0, %1" : "+v"(w20), "+v"(w30));
    asm volatile("v_permlane16_swap_b32 %0, %1" : "+v"(w20), "+v"(w30));
    asm volatile("v_permlane32_swap_b32 %0, %1" : "+v"(w21), "+v"(w31));
    asm volatile("v_permlane16_swap_b32 %0, %1" : "+v"(w21), "+v"(w31));
    u32x4 pq0; pq0[0] = w00; pq0[1] = w01; pq0[2] = w10; pq0[3] = w11;
    u32x4 pq1; pq1[0] = w20; pq1[1] = w21; pq1[2] = w30; pq1[3] = w31;
    const bf16x8 pa0 = __builtin_bit_cast(bf16x8, pq0);
    const bf16x8 pa1 = __builtin_bit_cast(bf16x8, pq1);
    const u16* VsC = Vs[cur];
    __builtin_amdgcn_s_setprio(1);
    // row-sum via MFMA: lsum4[r] += sum_k P[q=lo*4+r][k]
    lsum4 = __builtin_amdgcn_mfma_f32_16x16x32_bf16(pa0, ones, lsum4, 0, 0, 0);
    lsum4 = __builtin_amdgcn_mfma_f32_16x16x32_bf16(pa1, ones, lsum4, 0, 0, 0);
#pragma unroll
    for (int nj = 0; nj < 4; ++nj) {
      const int vr = nj * 16 + lr;   // d row
      const bf16x8 bv0 = *reinterpret_cast<const bf16x8*>((const char*)VsC + vr * 128 + ((lo ^ (vr & 7)) * 16));
      const bf16x8 bv1 = *reinterpret_cast<const bf16x8*>((const char*)VsC + vr * 128 + (((4 + lo) ^ (vr & 7)) * 16));
      acc[nj] = __builtin_amdgcn_mfma_f32_16x16x32_bf16(pa0, bv0, acc[nj], 0, 0, 0);
      acc[nj] = __builtin_amdgcn_mfma_f32_16x16x32_bf16(pa1, bv1, acc[nj], 0, 0, 0);
    }
    __builtin_amdgcn_s_setprio(0);
    cur ^= 1;
  }
  float lf[4];
#pragma unroll
  for (int r = 0; r < 4; ++r) lf[r] = 1.0f / lsum4[r];
  const size_t orow = (size_t)b * S + qt * 128 + w * 16 + lo * 4;
#pragma unroll
  for (int nj = 0; nj < 4; ++nj) {
    const int col = h * 64 + nj * 16 + lr;
#pragma unroll
    for (int r = 0; r < 4; ++r)
      Oa[(orow + r) * 2048 + col] = f2bf(acc[nj][r] * lf[r]);
  }
}

// ---------------- host ----------------
extern "C" void kernel_launch(void* const* d_in, const int* in_sizes, int n_in,
                              void* d_out, int out_size, void* d_ws, size_t ws_size,
                              hipStream_t stream) {
  const float* x  = (const float*)d_in[0];
  const float* Wq = (const float*)d_in[1];
  const float* bq = (const float*)d_in[2];
  const float* Wk = (const float*)d_in[3];
  const float* bk = (const float*)d_in[4];
  const float* Wv = (const float*)d_in[5];
  const float* bv = (const float*)d_in[6];
  const float* Wo = (const float*)d_in[7];
  const float* bo = (const float*)d_in[8];
  float* out = (float*)d_out;
  char* ws = (char*)d_ws;

  u16*   xb    = (u16*)(ws + 0);           // [4096][2048] bf16   16.78 MB
  u16*   wqkvT = (u16*)(ws + 16777216);    // [3072][2048] bf16   12.58 MB
  u16*   woT   = (u16*)(ws + 29360128);    // [2048][2048] bf16    8.39 MB
  u16*   qkv   = (u16*)(ws + 37748736);    // [4096][2560] bf16   20.97 MB (Q|K only)
  u16*   attn  = (u16*)(ws + 58720256);    // [4096][2048] bf16   16.78 MB
  u16*   vtg   = (u16*)(ws + 75497472);    // [2][8][64][2048] bf16 4.19 MB (V transposed)

  const float SCL = 0.125f * 1.44269504088896341f;  // 1/sqrt(64) * log2(e)

  k_prep<<<dim3(32, 32, 8), 256, 0, stream>>>(x, xb, Wq, Wk, Wv, Wo, wqkvT, woT);
  k_gemm<false><<<dim3(24, 32), 256, 0, stream>>>(xb, wqkvT, bq, bk, bv, qkv,
                                                  4096, 3072, 2048, 2048, 2560, 2048, SCL,
                                                  vtg, 2560, 2560);
  k_attn<<<dim3(16, 32, 2), 512, 0, stream>>>(qkv, vtg, attn);
  k_gemm<true><<<dim3(16, 32), 256, 0, stream>>>(attn, woT, bo, bo, bo, out,
                                                 4096, 2048, 2048, 2048, 4096, 0, 1.0f,
                                                 nullptr, 1 << 30, 2048);
}

// Round 19
// 247.889 us; speedup vs baseline: 1.1087x; 1.0014x over previous
//
#include <hip/hip_runtime.h>
#include <cstdint>
#include <cstddef>

typedef unsigned short u16;
typedef __bf16 bf16x8 __attribute__((ext_vector_type(8)));
typedef float f32x4 __attribute__((ext_vector_type(4)));
typedef unsigned short u16x4 __attribute__((ext_vector_type(4)));
typedef unsigned short u16x8 __attribute__((ext_vector_type(8)));
typedef uint32_t u32x4 __attribute__((ext_vector_type(4)));
typedef __attribute__((address_space(1))) unsigned int as1_uint;
typedef __attribute__((address_space(3))) unsigned int as3_uint;

__device__ __forceinline__ u16 f2bf(float f) {
  uint32_t u = __builtin_bit_cast(uint32_t, f);
  u += 0x7FFFu + ((u >> 16) & 1u);   // RNE to bf16
  return (u16)(u >> 16);
}

// one-instruction packed f32x2 -> bf16x2 (RNE), T12 recipe
__device__ __forceinline__ uint32_t cvtpk2bf(float a, float b) {
  uint32_t r;
  asm("v_cvt_pk_bf16_f32 %0, %1, %2" : "=v"(r) : "v"(a), "v"(b));
  return r;
}

__device__ __forceinline__ float max3f(float a, float b, float c) {
  return fmaxf(fmaxf(a, b), c);   // clang fuses to v_max3_f32
}

__device__ __forceinline__ void gld_lds16(const void* g, void* l) {
  __builtin_amdgcn_global_load_lds((as1_uint*)g, (as3_uint*)l, 16, 0, 0);
}

// ---------------- fused prep: weight transposes (z<4) + x cast (z>=4) ----------------
// casts via v_cvt_pk_bf16_f32 (1 instr per pair vs 7-op manual RNE).
__global__ __launch_bounds__(256) void k_prep(const float* __restrict__ x,
                                              u16* __restrict__ xb,
                                              const float* __restrict__ Wq,
                                              const float* __restrict__ Wk,
                                              const float* __restrict__ Wv,
                                              const float* __restrict__ Wo,
                                              u16* __restrict__ wqkvT,
                                              u16* __restrict__ woT) {
  constexpr int K = 2048;
  const int z = blockIdx.z;
  if (z >= 4) {
    int i = ((z - 4) * 1024 + blockIdx.y * 32 + blockIdx.x) * 256 + threadIdx.x;
    const float4* p = reinterpret_cast<const float4*>(x) + (size_t)i * 2;
    float4 a = p[0], b = p[1];
    u32x4 r;
    r[0] = cvtpk2bf(a.x, a.y); r[1] = cvtpk2bf(a.z, a.w);
    r[2] = cvtpk2bf(b.x, b.y); r[3] = cvtpk2bf(b.z, b.w);
    *reinterpret_cast<u32x4*>(xb + (size_t)i * 8) = r;
    return;
  }
  const float* W; u16* Wt; int N;
  if (z == 0)      { W = Wq; Wt = wqkvT;                        N = 2048; }
  else if (z == 1) { W = Wo; Wt = woT;                          N = 2048; }
  else if (z == 2) { W = Wk; Wt = wqkvT + (size_t)2048 * 2048;  N = 512;  }
  else             { W = Wv; Wt = wqkvT + (size_t)2560 * 2048;  N = 512;  }
  const int n0 = blockIdx.x * 64;
  if (n0 >= N) return;
  __shared__ u16 tile[64][72];
  const int k0 = blockIdx.y * 64;
  const int r = threadIdx.x >> 4;
  const int c4 = (threadIdx.x & 15) * 4;
#pragma unroll
  for (int i = 0; i < 4; ++i) {
    int kk = r + i * 16;
    float4 v = *reinterpret_cast<const float4*>(W + (size_t)(k0 + kk) * N + n0 + c4);
    uint32_t* dst = reinterpret_cast<uint32_t*>(&tile[kk][c4]);   // 8B-aligned (c4 mult of 4)
    dst[0] = cvtpk2bf(v.x, v.y);
    dst[1] = cvtpk2bf(v.z, v.w);
  }
  __syncthreads();
#pragma unroll
  for (int i = 0; i < 4; ++i) {
    int nn = r + i * 16;
    u16x4 o;
    o[0] = tile[c4 + 0][nn]; o[1] = tile[c4 + 1][nn];
    o[2] = tile[c4 + 2][nn]; o[3] = tile[c4 + 3][nn];
    *reinterpret_cast<u16x4*>(Wt + (size_t)(n0 + nn) * K + k0 + c4) = o;
  }
}

// ---------------- bf16 GEMM: C = (A @ Bt^T + bias(col)) * colscale ----------------
// 128x128 tile, BK=64, 4 waves (2x2), 16x16x32 MFMA; T1 bijective XCD swizzle.
// Columns >= vcol0 (bf16 out only) are written TRANSPOSED to vout[b][kvh][d][token].
template <bool F32OUT>
__global__ __launch_bounds__(256) void k_gemm(const u16* __restrict__ A,
                                              const u16* __restrict__ Bt,
                                              const float* __restrict__ b0,
                                              const float* __restrict__ b1,
                                              const float* __restrict__ b2,
                                              void* __restrict__ Cout,
                                              int M, int N, int K,
                                              int n1, int n2,
                                              int scaleN, float scaleV,
                                              u16* __restrict__ vout, int vcol0, int ldC) {
  __shared__ __align__(16) u16 As[128 * 64];
  __shared__ __align__(16) u16 Bs[128 * 64];
  const int id = blockIdx.y * gridDim.x + blockIdx.x;
  const int cpx = (gridDim.x * gridDim.y) >> 3;
  const int nid = (id & 7) * cpx + (id >> 3);
  const int m0 = (nid / gridDim.x) * 128, n0 = (nid % gridDim.x) * 128;
  const int tid = threadIdx.x;
  const int l = tid & 63, w = tid >> 6;
  const int wm = w >> 1, wn = w & 1;
  const int lr = l & 15, lo = l >> 4;
  const int srow = w * 8 + (l >> 3);
  const int sc = (l & 7) ^ ((l >> 3) & 7);
  f32x4 acc[4][4] = {};
  for (int kt = 0; kt < K; kt += 64) {
    __syncthreads();
#pragma unroll
    for (int it = 0; it < 4; ++it) {
      int row = it * 32 + srow;
      gld_lds16(A + (size_t)(m0 + row) * K + kt + sc * 8,
                (char*)As + (it * 32 + w * 8) * 128);
      gld_lds16(Bt + (size_t)(n0 + row) * K + kt + sc * 8,
                (char*)Bs + (it * 32 + w * 8) * 128);
    }
    __syncthreads();
    bf16x8 af[4][2], bfr[4][2];
#pragma unroll
    for (int mi = 0; mi < 4; ++mi) {
      int row = wm * 64 + mi * 16 + lr;
#pragma unroll
      for (int ks = 0; ks < 2; ++ks) {
        int ch = (ks * 4 + lo) ^ (row & 7);
        af[mi][ks] = *reinterpret_cast<const bf16x8*>((const char*)As + row * 128 + ch * 16);
      }
    }
#pragma unroll
    for (int nj = 0; nj < 4; ++nj) {
      int row = wn * 64 + nj * 16 + lr;
#pragma unroll
      for (int ks = 0; ks < 2; ++ks) {
        int ch = (ks * 4 + lo) ^ (row & 7);
        bfr[nj][ks] = *reinterpret_cast<const bf16x8*>((const char*)Bs + row * 128 + ch * 16);
      }
    }
#pragma unroll
    for (int mi = 0; mi < 4; ++mi)
#pragma unroll
      for (int nj = 0; nj < 4; ++nj) {
        acc[mi][nj] = __builtin_amdgcn_mfma_f32_16x16x32_bf16(af[mi][0], bfr[nj][0], acc[mi][nj], 0, 0, 0);
        acc[mi][nj] = __builtin_amdgcn_mfma_f32_16x16x32_bf16(af[mi][1], bfr[nj][1], acc[mi][nj], 0, 0, 0);
      }
  }
#pragma unroll
  for (int mi = 0; mi < 4; ++mi) {
    int row = m0 + wm * 64 + mi * 16 + lo * 4;
#pragma unroll
    for (int nj = 0; nj < 4; ++nj) {
      int col = n0 + wn * 64 + nj * 16 + lr;
      float bv = (col < n1) ? b0[col] : (col < n2 ? b1[col - n1] : b2[col - n2]);
      float scc = (col < scaleN) ? scaleV : 1.0f;
      float v[4];
#pragma unroll
      for (int r = 0; r < 4; ++r) v[r] = (acc[mi][nj][r] + bv) * scc;
      if (!F32OUT && col >= vcol0) {
        int d = col - vcol0;
        int kvh = d >> 6, dcol = d & 63;
        int bb = row >> 11, token = row & 2047;
        u16x4 o;
#pragma unroll
        for (int r = 0; r < 4; ++r) o[r] = f2bf(v[r]);
        *reinterpret_cast<u16x4*>(vout + (((size_t)(bb * 8 + kvh) * 64 + dcol) * 2048 + token)) = o;
      } else {
#pragma unroll
        for (int r = 0; r < 4; ++r) {
          if (F32OUT) ((float*)Cout)[(size_t)(row + r) * ldC + col] = v[r];
          else        ((u16*)Cout)[(size_t)(row + r) * ldC + col] = f2bf(v[r]);
        }
      }
    }
  }
}

// ---------------- flash attention: 512 threads, 8 waves x 16 q-rows ----------------
// grid (S/128, NQ, B); KVBLK=64; HD=64. launch_bounds(512,4). R18 structure.
// Fast-path ballot on PARTIAL maxima; shfl reductions only in the rare rescale branch.
// lsum MFMAs issued AFTER the PV cluster (lsum not needed until epilogue -> PV starts earlier).
__global__ __launch_bounds__(512, 4) void k_attn(const u16* __restrict__ QKV,
                                                 const u16* __restrict__ VT,
                                                 u16* __restrict__ Oa) {
  constexpr int S = 2048, LDQ = 2560;
  constexpr float THR = 8.0f;
  __shared__ __align__(16) u16 Ks[2][64 * 64];   // [key][d], chunk ^= row&7
  __shared__ __align__(16) u16 Vs[2][64 * 64];   // [d][key], chunk ^= row&7
  const int qt = blockIdx.x, h = blockIdx.y, b = blockIdx.z;
  const int kvh = h >> 2;
  const int tid = threadIdx.x, l = tid & 63, w = tid >> 6;   // w = 0..7
  const int lr = l & 15, lo = l >> 4;
  const size_t base = (size_t)b * S * LDQ;
  const u16* Qg = QKV + base + h * 64;
  const u16* Kg = QKV + base + 2048 + kvh * 64;
  const u16* Vg = VT + (size_t)(b * 8 + kvh) * 64 * 2048;
  const int qrow = qt * 128 + w * 16 + lr;
  const bf16x8 aq0 = *reinterpret_cast<const bf16x8*>(Qg + (size_t)qrow * LDQ + lo * 8);
  const bf16x8 aq1 = *reinterpret_cast<const bf16x8*>(Qg + (size_t)qrow * LDQ + 32 + lo * 8);
  // all-ones bf16 B-frag (layout-proof: every element 1.0)
  u32x4 onesw; onesw[0] = 0x3F803F80u; onesw[1] = 0x3F803F80u; onesw[2] = 0x3F803F80u; onesw[3] = 0x3F803F80u;
  const bf16x8 ones = __builtin_bit_cast(bf16x8, onesw);
  f32x4 acc[4] = {};
  f32x4 lsum4 = {};                              // row-sum in acc layout: lsum4[r] for q=lo*4+r
  float mrun = -1e30f;                           // per-q running max (uniform across lo group)
  const int krow = tid >> 3;                     // rows 0..63 across 8 waves
  const int ksc = (l & 7) ^ ((l >> 3) & 7);
  // ---- prologue: stage tile 0 (1 issue per operand covers all 64 rows) ----
  gld_lds16(Kg + (size_t)krow * LDQ + ksc * 8, (char*)Ks[0] + (w * 8) * 128);
  gld_lds16(Vg + (size_t)krow * 2048 + ksc * 8, (char*)Vs[0] + (w * 8) * 128);
  int cur = 0;
  for (int kt = 0; kt < S; kt += 64) {
    __syncthreads();   // implicit vmcnt(0): buf[cur] (K+V) ready
    if (kt + 64 < S) { // prefetch tile t+1; in flight across compute(t)
      const int nb = cur ^ 1, nk = kt + 64;
      gld_lds16(Kg + (size_t)(nk + krow) * LDQ + ksc * 8, (char*)Ks[nb] + (w * 8) * 128);
      gld_lds16(Vg + (size_t)krow * 2048 + nk + ksc * 8, (char*)Vs[nb] + (w * 8) * 128);
    }
    // QK^T swapped: p[t*4+r] = S[key=16t+4lo+r][q=lr]  (Q pre-scaled by log2e/sqrt(HD))
    float p[16];
    const u16* KsC = Ks[cur];
    __builtin_amdgcn_s_setprio(1);
#pragma unroll
    for (int t = 0; t < 4; ++t) {
      const int row = t * 16 + lr;
      bf16x8 k0 = *reinterpret_cast<const bf16x8*>((const char*)KsC + row * 128 + ((lo ^ (row & 7)) * 16));
      bf16x8 k1 = *reinterpret_cast<const bf16x8*>((const char*)KsC + row * 128 + (((4 + lo) ^ (row & 7)) * 16));
      f32x4 zz = {};
      zz = __builtin_amdgcn_mfma_f32_16x16x32_bf16(k0, aq0, zz, 0, 0, 0);
      zz = __builtin_amdgcn_mfma_f32_16x16x32_bf16(k1, aq1, zz, 0, 0, 0);
#pragma unroll
      for (int r = 0; r < 4; ++r) p[t * 4 + r] = zz[r];
    }
    __builtin_amdgcn_s_setprio(0);
    // partial (in-lane) tile max for q=lr: max3 tree only — NO cross-lane ops
    float m0 = max3f(p[0], p[1], p[2]);
    float m1 = max3f(p[3], p[4], p[5]);
    float m2 = max3f(p[6], p[7], p[8]);
    float m3 = max3f(p[9], p[10], p[11]);
    float m4 = max3f(p[12], p[13], p[14]);
    float tmp = fmaxf(max3f(m0, m1, m2), max3f(m3, m4, p[15]));
    // __all over partial maxima == "full per-q max <= thr for every q"
    if (__all(tmp <= mrun + THR)) {
      // defer-max: keep stale mrun; p bounded by 2^THR
#pragma unroll
      for (int i = 0; i < 16; ++i) p[i] = __builtin_amdgcn_exp2f(p[i] - mrun);
    } else {
      // rare path: full cross-lane reduce, then rescale
      float tm = fmaxf(tmp, __shfl_xor(tmp, 16, 64));
      tm = fmaxf(tm, __shfl_xor(tm, 32, 64));
      float mnew = fmaxf(mrun, tm);
      float alpha = __builtin_amdgcn_exp2f(mrun - mnew);
      mrun = mnew;
#pragma unroll
      for (int i = 0; i < 16; ++i) p[i] = __builtin_amdgcn_exp2f(p[i] - mnew);
#pragma unroll
      for (int r = 0; r < 4; ++r) {
        float ar = __shfl(alpha, lo * 4 + r, 64);   // alpha for acc-row q=lo*4+r
        lsum4[r] *= ar;
#pragma unroll
        for (int nj = 0; nj < 4; ++nj) acc[nj][r] *= ar;
      }
    }
    // pack P pairs with v_cvt_pk_bf16_f32 (1 instr each)
    uint32_t w00 = cvtpk2bf(p[0], p[1]),   w01 = cvtpk2bf(p[2], p[3]);
    uint32_t w10 = cvtpk2bf(p[4], p[5]),   w11 = cvtpk2bf(p[6], p[7]);
    uint32_t w20 = cvtpk2bf(p[8], p[9]),   w21 = cvtpk2bf(p[10], p[11]);
    uint32_t w30 = cvtpk2bf(p[12], p[13]), w31 = cvtpk2bf(p[14], p[15]);
    // redistribute to A-frag layout: lane lo needs keys 8lo..8lo+7 (pa0), +32 (pa1)
    asm volatile("v_permlane32_swap_b32 %0, %1" : "+v"(w00), "+v"(w10));
    asm volatile("v_permlane16_swap_b32 %0, %1" : "+v"(w00), "+v"(w10));  // w00=d0 w10=d2
    asm volatile("v_permlane32_swap_b32 %0, %1" : "+v"(w01), "+v"(w11));
    asm volatile("v_permlane16_swap_b32 %0, %1" : "+v"(w01), "+v"(w11));  // w01=d1 w11=d3
    asm volatile("v_permlane32_swap_b32 %0, %1" : "+v"(w20), "+v"(w30));
    asm volatile("v_permlane16_swap_b32 %0, %1" : "+v"(w20), "+v"(w30));
    asm volatile("v_permlane32_swap_b32 %0, %1" : "+v"(w21), "+v"(w31));
    asm volatile("v_permlane16_swap_b32 %0, %1" : "+v"(w21), "+v"(w31));
    u32x4 pq0; pq0[0] = w00; pq0[1] = w01; pq0[2] = w10; pq0[3] = w11;
    u32x4 pq1; pq1[0] = w20; pq1[1] = w21; pq1[2] = w30; pq1[3] = w31;
    const bf16x8 pa0 = __builtin_bit_cast(bf16x8, pq0);
    const bf16x8 pa1 = __builtin_bit_cast(bf16x8, pq1);
    const u16* VsC = Vs[cur];
    __builtin_amdgcn_s_setprio(1);
#pragma unroll
    for (int nj = 0; nj < 4; ++nj) {
      const int vr = nj * 16 + lr;   // d row
      const bf16x8 bv0 = *reinterpret_cast<const bf16x8*>((const char*)VsC + vr * 128 + ((lo ^ (vr & 7)) * 16));
      const bf16x8 bv1 = *reinterpret_cast<const bf16x8*>((const char*)VsC + vr * 128 + (((4 + lo) ^ (vr & 7)) * 16));
      acc[nj] = __builtin_amdgcn_mfma_f32_16x16x32_bf16(pa0, bv0, acc[nj], 0, 0, 0);
      acc[nj] = __builtin_amdgcn_mfma_f32_16x16x32_bf16(pa1, bv1, acc[nj], 0, 0, 0);
    }
    // row-sum via MFMA AFTER PV (independent of PV; needed only in epilogue)
    lsum4 = __builtin_amdgcn_mfma_f32_16x16x32_bf16(pa0, ones, lsum4, 0, 0, 0);
    lsum4 = __builtin_amdgcn_mfma_f32_16x16x32_bf16(pa1, ones, lsum4, 0, 0, 0);
    __builtin_amdgcn_s_setprio(0);
    cur ^= 1;
  }
  float lf[4];
#pragma unroll
  for (int r = 0; r < 4; ++r) lf[r] = __builtin_amdgcn_rcpf(lsum4[r]);  // ~22-bit, ample for bf16 out
  const size_t orow = (size_t)b * S + qt * 128 + w * 16 + lo * 4;
#pragma unroll
  for (int nj = 0; nj < 4; ++nj) {
    const int col = h * 64 + nj * 16 + lr;
#pragma unroll
    for (int r = 0; r < 4; ++r)
      Oa[(orow + r) * 2048 + col] = f2bf(acc[nj][r] * lf[r]);
  }
}

// ---------------- host ----------------
extern "C" void kernel_launch(void* const* d_in, const int* in_sizes, int n_in,
                              void* d_out, int out_size, void* d_ws, size_t ws_size,
                              hipStream_t stream) {
  const float* x  = (const float*)d_in[0];
  const float* Wq = (const float*)d_in[1];
  const float* bq = (const float*)d_in[2];
  const float* Wk = (const float*)d_in[3];
  const float* bk = (const float*)d_in[4];
  const float* Wv = (const float*)d_in[5];
  const float* bv = (const float*)d_in[6];
  const float* Wo = (const float*)d_in[7];
  const float* bo = (const float*)d_in[8];
  float* out = (float*)d_out;
  char* ws = (char*)d_ws;

  u16*   xb    = (u16*)(ws + 0);           // [4096][2048] bf16   16.78 MB
  u16*   wqkvT = (u16*)(ws + 16777216);    // [3072][2048] bf16   12.58 MB
  u16*   woT   = (u16*)(ws + 29360128);    // [2048][2048] bf16    8.39 MB
  u16*   qkv   = (u16*)(ws + 37748736);    // [4096][2560] bf16   20.97 MB (Q|K only)
  u16*   attn  = (u16*)(ws + 58720256);    // [4096][2048] bf16   16.78 MB
  u16*   vtg   = (u16*)(ws + 75497472);    // [2][8][64][2048] bf16 4.19 MB (V transposed)

  const float SCL = 0.125f * 1.44269504088896341f;  // 1/sqrt(64) * log2(e)

  k_prep<<<dim3(32, 32, 8), 256, 0, stream>>>(x, xb, Wq, Wk, Wv, Wo, wqkvT, woT);
  k_gemm<false><<<dim3(24, 32), 256, 0, stream>>>(xb, wqkvT, bq, bk, bv, qkv,
                                                  4096, 3072, 2048, 2048, 2560, 2048, SCL,
                                                  vtg, 2560, 2560);
  k_attn<<<dim3(16, 32, 2), 512, 0, stream>>>(qkv, vtg, attn);
  k_gemm<true><<<dim3(16, 32), 256, 0, stream>>>(attn, woT, bo, bo, bo, out,
                                                 4096, 2048, 2048, 2048, 4096, 0, 1.0f,
                                                 nullptr, 1 << 30, 2048);
}